// Round 10
// baseline (329.791 us; speedup 1.0000x reference)
//
#include <hip/hip_runtime.h>

// INSTRUMENTATION ROUND 2.
// fast   : exact R8 best kernel -> d_out (correctness + timing continuity).
// heavy_a: R8 structure, k-loop x8           -> counters for incumbent.
// heavy_b: R8 + pair-packed coeffs (3 b128 / 2k, -25% LDS), x8.
// heavy_c: 2 pts/thread, 2048 blocks, 8 waves/SIMD, x8.
// heavy_X/8 = true per-pass cost of each structure; VALUBusy/Occupancy
// decide issue-bound vs LDS-bound vs latency-bound.

typedef float v2f __attribute__((ext_vector_type(2)));

constexpr int B = 512;
constexpr int K = 64;
constexpr int C = 2048;
constexpr int BLOCK = 256;
constexpr int REP = 8;

// Quadratic-form coefficients for one (b,k):
// e = A x^2 + B y^2 + C xy + D x + E y + F  (log2 domain, wn folded into F).
__device__ __forceinline__ void coef6(const float* __restrict__ p6,
                                      float& A, float& Bc, float& Cc,
                                      float& D, float& E, float& F) {
    const float w  = p6[0], m1 = p6[1], m2 = p6[2];
    const float s1 = p6[3], s2 = p6[4], r  = p6[5];
    const float omr2 = fmaf(-r, r, 1.0f);
    const float inv  = 1.0f / omr2;
    const float g    = 0.7213475204444817f * inv;
    const float i1   = 1.0f / s1;
    const float i2   = 1.0f / s2;
    const float p    = g * i1 * i1;
    const float q    = g * i2 * i2;
    const float s    = 2.0f * r * g * i1 * i2;
    A  = -p;
    Bc = -q;
    Cc = s;
    D  = fmaf(2.0f * p, m1, -s * m2);
    E  = fmaf(2.0f * q, m2, -s * m1);
    const float wn = w * 0.15915494309189535f * i1 * i2 * sqrtf(inv);
    const float L  = log2f(fmaxf(wn, 1e-37f));
    F  = fmaf(-p, m1 * m1, fmaf(-q, m2 * m2, fmaf(s, m1 * m2, L)));
}

__device__ __forceinline__ v2f splat(float v) { return (v2f){v, v}; }

__device__ __forceinline__ void eval2(const v2f& A2, const v2f& B2, const v2f& C2,
                                      const v2f& D2, const v2f& E2, const v2f& F2,
                                      const v2f& xx, const v2f& yy, const v2f& xy,
                                      const v2f& xp, const v2f& yp, v2f& acc) {
    v2f e = __builtin_elementwise_fma(A2, xx, F2);
    e     = __builtin_elementwise_fma(B2, yy, e);
    e     = __builtin_elementwise_fma(C2, xy, e);
    e     = __builtin_elementwise_fma(D2, xp, e);
    e     = __builtin_elementwise_fma(E2, yp, e);
    v2f ex;
    ex.x = __builtin_amdgcn_exp2f(e.x);
    ex.y = __builtin_amdgcn_exp2f(e.y);
    acc = acc + ex;
}

// ---------------- fast: exact R8 ----------------
__global__ __launch_bounds__(BLOCK, 4) void fast_k(
    const float* __restrict__ mo, const float* __restrict__ X,
    float* __restrict__ out)
{
    __shared__ float4 P[K][2];
    const int bid = blockIdx.x;
    const int b = bid >> 1, h = bid & 1, t = threadIdx.x;

    if (t < K) {
        float A, Bc, Cc, D, E, F;
        coef6(mo + ((size_t)(b * K + t)) * 6, A, Bc, Cc, D, E, F);
        P[t][0] = make_float4(A, Bc, Cc, D);
        P[t][1] = make_float4(E, F, 0.0f, 0.0f);
    }
    __syncthreads();

    const float4* Xb = (const float4*)(X + ((size_t)b * C + (size_t)h * 1024) * 2);
    const float4 xv0 = Xb[t];
    const float4 xv1 = Xb[t + BLOCK];
    const v2f xp[2] = { {xv0.x, xv0.z}, {xv1.x, xv1.z} };
    const v2f yp[2] = { {xv0.y, xv0.w}, {xv1.y, xv1.w} };
    const v2f xx[2] = { xp[0] * xp[0], xp[1] * xp[1] };
    const v2f yy[2] = { yp[0] * yp[0], yp[1] * yp[1] };
    const v2f xy[2] = { xp[0] * yp[0], xp[1] * yp[1] };
    v2f acc[2] = { {0.0f, 0.0f}, {0.0f, 0.0f} };

#pragma unroll 4
    for (int k = 0; k < K; ++k) {
        const float4 c0 = P[k][0];
        const float4 c1 = P[k][1];
        const v2f A2 = splat(c0.x), B2 = splat(c0.y), C2 = splat(c0.z);
        const v2f D2 = splat(c0.w), E2 = splat(c1.x), F2 = splat(c1.y);
#pragma unroll
        for (int j = 0; j < 2; ++j)
            eval2(A2, B2, C2, D2, E2, F2, xx[j], yy[j], xy[j], xp[j], yp[j], acc[j]);
    }

    float2* ob = (float2*)(out + (size_t)b * C + (size_t)h * 1024);
    ob[t]         = make_float2(acc[0].x, acc[0].y);
    ob[t + BLOCK] = make_float2(acc[1].x, acc[1].y);
}

// ---------------- heavy_a: R8 structure x REP ----------------
__global__ __launch_bounds__(BLOCK, 4) void heavy_a(
    const float* __restrict__ mo, const float* __restrict__ X,
    float* __restrict__ out)
{
    __shared__ float4 P[K][2];
    const int bid = blockIdx.x;
    const int b = bid >> 1, h = bid & 1, t = threadIdx.x;

    if (t < K) {
        float A, Bc, Cc, D, E, F;
        coef6(mo + ((size_t)(b * K + t)) * 6, A, Bc, Cc, D, E, F);
        P[t][0] = make_float4(A, Bc, Cc, D);
        P[t][1] = make_float4(E, F, 0.0f, 0.0f);
    }
    __syncthreads();

    const float4* Xb = (const float4*)(X + ((size_t)b * C + (size_t)h * 1024) * 2);
    const float4 xv0 = Xb[t];
    const float4 xv1 = Xb[t + BLOCK];
    const v2f xp0[2] = { {xv0.x, xv0.z}, {xv1.x, xv1.z} };
    const v2f yp[2]  = { {xv0.y, xv0.w}, {xv1.y, xv1.w} };
    v2f acc[2] = { {0.0f, 0.0f}, {0.0f, 0.0f} };

#pragma unroll 1
    for (int rep = 0; rep < REP; ++rep) {
        const float eps = (float)rep * 1e-30f;
        const v2f ve = { eps, eps };
        const v2f xp[2] = { xp0[0] + ve, xp0[1] + ve };
        const v2f xx[2] = { xp[0] * xp[0], xp[1] * xp[1] };
        const v2f yy[2] = { yp[0] * yp[0], yp[1] * yp[1] };
        const v2f xy[2] = { xp[0] * yp[0], xp[1] * yp[1] };
#pragma unroll 4
        for (int k = 0; k < K; ++k) {
            const float4 c0 = P[k][0];
            const float4 c1 = P[k][1];
            const v2f A2 = splat(c0.x), B2 = splat(c0.y), C2 = splat(c0.z);
            const v2f D2 = splat(c0.w), E2 = splat(c1.x), F2 = splat(c1.y);
#pragma unroll
            for (int j = 0; j < 2; ++j)
                eval2(A2, B2, C2, D2, E2, F2, xx[j], yy[j], xy[j], xp[j], yp[j], acc[j]);
        }
    }

    float2* ob = (float2*)(out + (size_t)b * C + (size_t)h * 1024);
    ob[t]         = make_float2(acc[0].x, acc[0].y);
    ob[t + BLOCK] = make_float2(acc[1].x, acc[1].y);
}

// ---------------- heavy_b: pair-packed coeffs (3 b128 / 2k) x REP ----------------
__global__ __launch_bounds__(BLOCK, 4) void heavy_b(
    const float* __restrict__ mo, const float* __restrict__ X,
    float* __restrict__ out)
{
    __shared__ float Pc[(K / 2) * 12];   // 1536 B, 48 B per k-pair
    const int bid = blockIdx.x;
    const int b = bid >> 1, h = bid & 1, t = threadIdx.x;

    if (t < K) {
        float A, Bc, Cc, D, E, F;
        coef6(mo + ((size_t)(b * K + t)) * 6, A, Bc, Cc, D, E, F);
        float* dst = &Pc[(t >> 1) * 12 + (t & 1) * 6];
        dst[0] = A; dst[1] = Bc; dst[2] = Cc;
        dst[3] = D; dst[4] = E;  dst[5] = F;
    }
    __syncthreads();

    const float4* Xb = (const float4*)(X + ((size_t)b * C + (size_t)h * 1024) * 2);
    const float4 xv0 = Xb[t];
    const float4 xv1 = Xb[t + BLOCK];
    const v2f xp0[2] = { {xv0.x, xv0.z}, {xv1.x, xv1.z} };
    const v2f yp[2]  = { {xv0.y, xv0.w}, {xv1.y, xv1.w} };
    v2f acc[2] = { {0.0f, 0.0f}, {0.0f, 0.0f} };

    const float4* Pq = (const float4*)Pc;

#pragma unroll 1
    for (int rep = 0; rep < REP; ++rep) {
        const float eps = (float)rep * 1e-30f;
        const v2f ve = { eps, eps };
        const v2f xp[2] = { xp0[0] + ve, xp0[1] + ve };
        const v2f xx[2] = { xp[0] * xp[0], xp[1] * xp[1] };
        const v2f yy[2] = { yp[0] * yp[0], yp[1] * yp[1] };
        const v2f xy[2] = { xp[0] * yp[0], xp[1] * yp[1] };
#pragma unroll 4
        for (int pr = 0; pr < K / 2; ++pr) {
            const float4 q0 = Pq[pr * 3 + 0];   // A0,B0,C0,D0
            const float4 q1 = Pq[pr * 3 + 1];   // E0,F0,A1,B1
            const float4 q2 = Pq[pr * 3 + 2];   // C1,D1,E1,F1
            {
                const v2f A2 = splat(q0.x), B2 = splat(q0.y), C2 = splat(q0.z);
                const v2f D2 = splat(q0.w), E2 = splat(q1.x), F2 = splat(q1.y);
#pragma unroll
                for (int j = 0; j < 2; ++j)
                    eval2(A2, B2, C2, D2, E2, F2, xx[j], yy[j], xy[j], xp[j], yp[j], acc[j]);
            }
            {
                const v2f A2 = splat(q1.z), B2 = splat(q1.w), C2 = splat(q2.x);
                const v2f D2 = splat(q2.y), E2 = splat(q2.z), F2 = splat(q2.w);
#pragma unroll
                for (int j = 0; j < 2; ++j)
                    eval2(A2, B2, C2, D2, E2, F2, xx[j], yy[j], xy[j], xp[j], yp[j], acc[j]);
            }
        }
    }

    float2* ob = (float2*)(out + (size_t)b * C + (size_t)h * 1024);
    ob[t]         = make_float2(acc[0].x, acc[0].y);
    ob[t + BLOCK] = make_float2(acc[1].x, acc[1].y);
}

// ---------------- heavy_c: 2 pts/thread, 2048 blocks, 8 waves/SIMD, x REP ----------------
__global__ __launch_bounds__(BLOCK, 8) void heavy_c(
    const float* __restrict__ mo, const float* __restrict__ X,
    float* __restrict__ out)
{
    __shared__ float4 P[K][2];
    const int bid = blockIdx.x;
    const int b = bid >> 2, q = bid & 3, t = threadIdx.x;   // quarter = 512 pts

    if (t < K) {
        float A, Bc, Cc, D, E, F;
        coef6(mo + ((size_t)(b * K + t)) * 6, A, Bc, Cc, D, E, F);
        P[t][0] = make_float4(A, Bc, Cc, D);
        P[t][1] = make_float4(E, F, 0.0f, 0.0f);
    }
    __syncthreads();

    const float4* Xb = (const float4*)(X + ((size_t)b * C + (size_t)q * 512) * 2);
    const float4 xv = Xb[t];
    const v2f xq0 = { xv.x, xv.z };
    const v2f yq  = { xv.y, xv.w };
    v2f acc = { 0.0f, 0.0f };

#pragma unroll 1
    for (int rep = 0; rep < REP; ++rep) {
        const float eps = (float)rep * 1e-30f;
        const v2f ve = { eps, eps };
        const v2f xq = xq0 + ve;
        const v2f xx = xq * xq;
        const v2f yy = yq * yq;
        const v2f xy = xq * yq;
#pragma unroll 4
        for (int k = 0; k < K; ++k) {
            const float4 c0 = P[k][0];
            const float4 c1 = P[k][1];
            const v2f A2 = splat(c0.x), B2 = splat(c0.y), C2 = splat(c0.z);
            const v2f D2 = splat(c0.w), E2 = splat(c1.x), F2 = splat(c1.y);
            eval2(A2, B2, C2, D2, E2, F2, xx, yy, xy, xq, yq, acc);
        }
    }

    float2* ob = (float2*)(out + (size_t)b * C + (size_t)q * 512);
    ob[t] = make_float2(acc.x, acc.y);
}

extern "C" void kernel_launch(void* const* d_in, const int* in_sizes, int n_in,
                              void* d_out, int out_size, void* d_ws, size_t ws_size,
                              hipStream_t stream) {
    const float* mo = (const float*)d_in[0];
    const float* X  = (const float*)d_in[1];
    float* out      = (float*)d_out;
    float* wsA      = (float*)d_ws;
    float* wsB      = wsA + (size_t)B * C;
    float* wsC      = wsB + (size_t)B * C;

    fast_k <<<dim3(B * 2), dim3(BLOCK), 0, stream>>>(mo, X, out);
    heavy_a<<<dim3(B * 2), dim3(BLOCK), 0, stream>>>(mo, X, wsA);
    heavy_b<<<dim3(B * 2), dim3(BLOCK), 0, stream>>>(mo, X, wsB);
    heavy_c<<<dim3(B * 4), dim3(BLOCK), 0, stream>>>(mo, X, wsC);
}

// Round 11
// 70.943 us; speedup vs baseline: 4.6487x; 4.6487x over previous
//
#include <hip/hip_runtime.h>

// out[b,c] = sum_k w[b,k] * BivariateNormalPDF(X[b,c]; params[b,k])
// B=512, K=64, C=2048.
//
// Round 11: R8 skeleton (1024 blocks, 256 thr, 4 pts/thread, 4 blocks/CU)
// with PAIR-PACKED coefficients: one 48 B record per k-pair ->
// 3 ds_read_b128 per 2 k's (1.5 reads/wave-iter, was 2). The CU LDS pipe
// (16 waves x reads x ~12cy) is the measured bottleneck (~10us in R8;
// model says 7.7us at 1.5 reads/iter). Unroll 8 keeps 12 outstanding
// reads (< lgkmcnt 15) so the compiler can pipeline read groups.
// Exponent in log2 domain (wn folded into F):
//   e = A x^2 + B y^2 + C xy + D x + E y + F;  acc += exp2(e)
// x^2,y^2,xy hoisted per thread; splats fold to VOP3P op_sel.

typedef float v2f __attribute__((ext_vector_type(2)));

constexpr int B = 512;
constexpr int K = 64;
constexpr int C = 2048;
constexpr int BLOCK = 256;
constexpr int HALVES = 2;        // each batch's C range split across 2 blocks
constexpr int CH = C / HALVES;   // 1024 points per block -> 4 per thread

__device__ __forceinline__ v2f splat(float v) { return (v2f){v, v}; }

__device__ __forceinline__ void eval2(const v2f& A2, const v2f& B2, const v2f& C2,
                                      const v2f& D2, const v2f& E2, const v2f& F2,
                                      const v2f& xx, const v2f& yy, const v2f& xy,
                                      const v2f& xp, const v2f& yp, v2f& acc) {
    v2f e = __builtin_elementwise_fma(A2, xx, F2);
    e     = __builtin_elementwise_fma(B2, yy, e);
    e     = __builtin_elementwise_fma(C2, xy, e);
    e     = __builtin_elementwise_fma(D2, xp, e);
    e     = __builtin_elementwise_fma(E2, yp, e);
    v2f ex;
    ex.x = __builtin_amdgcn_exp2f(e.x);
    ex.y = __builtin_amdgcn_exp2f(e.y);
    acc = acc + ex;
}

__global__ __launch_bounds__(BLOCK, 4) void mixture_kernel(
    const float* __restrict__ mo,   // (B, K, 6)
    const float* __restrict__ X,    // (B, C, 2)
    float* __restrict__ out)        // (B, C)
{
    __shared__ float Pc[(K / 2) * 12];   // 48 B per k-pair, 1536 B total

    const int bid = blockIdx.x;
    const int b   = bid >> 1;
    const int h   = bid & 1;
    const int t   = threadIdx.x;

    if (t < K) {
        const float* p6 = mo + ((size_t)(b * K + t)) * 6;
        const float w  = p6[0];
        const float m1 = p6[1];
        const float m2 = p6[2];
        const float s1 = p6[3];
        const float s2 = p6[4];
        const float r  = p6[5];

        const float omr2 = fmaf(-r, r, 1.0f);
        const float inv  = 1.0f / omr2;
        const float g    = 0.7213475204444817f * inv;   // 0.5*log2(e)/omr2
        const float i1   = 1.0f / s1;
        const float i2   = 1.0f / s2;
        const float p    = g * i1 * i1;
        const float q    = g * i2 * i2;
        const float s    = 2.0f * r * g * i1 * i2;
        const float A    = -p;
        const float Bc   = -q;
        const float Cc   = s;
        const float D    = fmaf(2.0f * p, m1, -s * m2);
        const float E    = fmaf(2.0f * q, m2, -s * m1);
        const float wn   = w * 0.15915494309189535f * i1 * i2 * sqrtf(inv);
        const float L    = log2f(fmaxf(wn, 1e-37f));
        const float F    = fmaf(-p, m1 * m1, fmaf(-q, m2 * m2, fmaf(s, m1 * m2, L)));

        // k-pair record: even k -> floats 0..5, odd k -> floats 6..11.
        float* dst = &Pc[(t >> 1) * 12 + (t & 1) * 6];
        dst[0] = A; dst[1] = Bc; dst[2] = Cc;
        dst[3] = D; dst[4] = E;  dst[5] = F;
    }
    __syncthreads();

    // 4 points/thread: 2 coalesced float4 loads, repacked (x,x)/(y,y);
    // x^2, y^2, x*y hoisted.
    const float4* Xb = (const float4*)(X + ((size_t)b * C + (size_t)h * CH) * 2);
    const float4 xv0 = Xb[t];
    const float4 xv1 = Xb[t + BLOCK];

    const v2f xp[2] = { {xv0.x, xv0.z}, {xv1.x, xv1.z} };
    const v2f yp[2] = { {xv0.y, xv0.w}, {xv1.y, xv1.w} };
    const v2f xx[2] = { xp[0] * xp[0], xp[1] * xp[1] };
    const v2f yy[2] = { yp[0] * yp[0], yp[1] * yp[1] };
    const v2f xy[2] = { xp[0] * yp[0], xp[1] * yp[1] };
    v2f acc[2] = { {0.0f, 0.0f}, {0.0f, 0.0f} };

    const float4* Pq = (const float4*)Pc;

#pragma unroll 4
    for (int pr = 0; pr < K / 2; ++pr) {
        const float4 q0 = Pq[pr * 3 + 0];   // A0,B0,C0,D0   (broadcast)
        const float4 q1 = Pq[pr * 3 + 1];   // E0,F0,A1,B1
        const float4 q2 = Pq[pr * 3 + 2];   // C1,D1,E1,F1

        {   // even k of the pair
            const v2f A2 = splat(q0.x), B2 = splat(q0.y), C2 = splat(q0.z);
            const v2f D2 = splat(q0.w), E2 = splat(q1.x), F2 = splat(q1.y);
#pragma unroll
            for (int j = 0; j < 2; ++j)
                eval2(A2, B2, C2, D2, E2, F2, xx[j], yy[j], xy[j], xp[j], yp[j], acc[j]);
        }
        {   // odd k of the pair
            const v2f A2 = splat(q1.z), B2 = splat(q1.w), C2 = splat(q2.x);
            const v2f D2 = splat(q2.y), E2 = splat(q2.z), F2 = splat(q2.w);
#pragma unroll
            for (int j = 0; j < 2; ++j)
                eval2(A2, B2, C2, D2, E2, F2, xx[j], yy[j], xy[j], xp[j], yp[j], acc[j]);
        }
    }

    float2* ob = (float2*)(out + (size_t)b * C + (size_t)h * CH);
    ob[t]         = make_float2(acc[0].x, acc[0].y);
    ob[t + BLOCK] = make_float2(acc[1].x, acc[1].y);
}

extern "C" void kernel_launch(void* const* d_in, const int* in_sizes, int n_in,
                              void* d_out, int out_size, void* d_ws, size_t ws_size,
                              hipStream_t stream) {
    const float* mo = (const float*)d_in[0];   // (B,K,6)
    const float* X  = (const float*)d_in[1];   // (B,C,2)
    float* out      = (float*)d_out;           // (B,C)

    mixture_kernel<<<dim3(B * HALVES), dim3(BLOCK), 0, stream>>>(mo, X, out);
}

// Round 12
// 69.753 us; speedup vs baseline: 4.7280x; 1.0171x over previous
//
#include <hip/hip_runtime.h>

// out[b,c] = sum_k w[b,k] * BivariateNormalPDF(X[b,c]; params[b,k])
// B=512, K=64, C=2048.
//
// Round 12: R8 skeleton (1024 blocks, 256 thr, 4 pts/thread, 4 blocks/CU,
// LDS [A,B,C,D][E,F,-,-] per k, 2 ds_read_b128/k-iter) with the inner
// quadratic evaluated via VOP3P op_sel inline asm: scalar coefficients are
// splatted INSIDE each v_pk_fma_f32 (op_sel lo/lo or hi/hi on the raw
// ds_read result registers) -> zero splat v_movs (the R8 residual ~1.3us).
// Horner form, log2 domain, wn folded into F:
//   u = A*x + (C*y + D);  v = B*y + E;  e = x*u + (y*v + F);
//   acc += exp2(e)   [per packed pair: 5 pk_fma + 1 pk_add + 2 v_exp]
// Per k-iter per wave: 12 pk + 4 exp + 2 ds_read_b128, nothing else.

typedef float v2f __attribute__((ext_vector_type(2)));

constexpr int B = 512;
constexpr int K = 64;
constexpr int C = 2048;
constexpr int BLOCK = 256;
constexpr int HALVES = 2;        // each batch's C range split across 2 blocks
constexpr int CH = C / HALVES;   // 1024 points per block -> 4 per thread

__global__ __launch_bounds__(BLOCK, 4) void mixture_kernel(
    const float* __restrict__ mo,   // (B, K, 6)
    const float* __restrict__ X,    // (B, C, 2)
    float* __restrict__ out)        // (B, C)
{
    __shared__ float4 P[K][2];      // [A,B,C,D], [E,F,-,-]

    const int bid = blockIdx.x;
    const int b   = bid >> 1;
    const int h   = bid & 1;
    const int t   = threadIdx.x;

    if (t < K) {
        const float* p6 = mo + ((size_t)(b * K + t)) * 6;
        const float w  = p6[0];
        const float m1 = p6[1];
        const float m2 = p6[2];
        const float s1 = p6[3];
        const float s2 = p6[4];
        const float r  = p6[5];

        const float omr2 = fmaf(-r, r, 1.0f);
        const float inv  = 1.0f / omr2;
        const float g    = 0.7213475204444817f * inv;   // 0.5*log2(e)/omr2
        const float i1   = 1.0f / s1;
        const float i2   = 1.0f / s2;
        const float p    = g * i1 * i1;
        const float q    = g * i2 * i2;
        const float s    = 2.0f * r * g * i1 * i2;
        const float A    = -p;
        const float Bc   = -q;
        const float Cc   = s;
        const float D    = fmaf(2.0f * p, m1, -s * m2);
        const float E    = fmaf(2.0f * q, m2, -s * m1);
        const float wn   = w * 0.15915494309189535f * i1 * i2 * sqrtf(inv);
        const float L    = log2f(fmaxf(wn, 1e-37f));
        const float F    = fmaf(-p, m1 * m1, fmaf(-q, m2 * m2, fmaf(s, m1 * m2, L)));

        P[t][0] = make_float4(A, Bc, Cc, D);
        P[t][1] = make_float4(E, F, 0.0f, 0.0f);
    }
    __syncthreads();

    // 4 points/thread: 2 coalesced float4 loads, repacked (x,x)/(y,y).
    const float4* Xb = (const float4*)(X + ((size_t)b * C + (size_t)h * CH) * 2);
    const float4 xv0 = Xb[t];
    const float4 xv1 = Xb[t + BLOCK];

    const v2f xp[2] = { {xv0.x, xv0.z}, {xv1.x, xv1.z} };
    const v2f yp[2] = { {xv0.y, xv0.w}, {xv1.y, xv1.w} };
    v2f acc[2] = { {0.0f, 0.0f}, {0.0f, 0.0f} };

#pragma unroll 4
    for (int k = 0; k < K; ++k) {
        const float4 c0 = P[k][0];           // A,B | C,D  (two VGPR pairs)
        const float4 c1 = P[k][1];           // E,F | -,-
        const v2f cAB = { c0.x, c0.y };      // subregister pair of c0
        const v2f cCD = { c0.z, c0.w };
        const v2f cEF = { c1.x, c1.y };

#pragma unroll
        for (int j = 0; j < 2; ++j) {
            v2f u, vv, e;
            // u = splat(C)*y + splat(D)     [C=lo(cCD), D=hi(cCD)]
            asm("v_pk_fma_f32 %0, %1, %2, %1 op_sel:[0,0,1] op_sel_hi:[0,1,1]"
                : "=v"(u) : "v"(cCD), "v"(yp[j]));
            // u = splat(A)*x + u            [A=lo(cAB)]
            asm("v_pk_fma_f32 %0, %1, %2, %0 op_sel:[0,0,0] op_sel_hi:[0,1,1]"
                : "+v"(u) : "v"(cAB), "v"(xp[j]));
            // vv = splat(B)*y + splat(E)    [B=hi(cAB), E=lo(cEF)]
            asm("v_pk_fma_f32 %0, %1, %2, %3 op_sel:[1,0,0] op_sel_hi:[1,1,0]"
                : "=v"(vv) : "v"(cAB), "v"(yp[j]), "v"(cEF));
            // e = y*vv + splat(F)           [F=hi(cEF)]
            asm("v_pk_fma_f32 %0, %1, %2, %3 op_sel:[0,0,1] op_sel_hi:[1,1,1]"
                : "=v"(e) : "v"(yp[j]), "v"(vv), "v"(cEF));
            // e = x*u + e  (plain packed fma, no op_sel needed)
            e = __builtin_elementwise_fma(xp[j], u, e);
            v2f ex;
            ex.x = __builtin_amdgcn_exp2f(e.x);
            ex.y = __builtin_amdgcn_exp2f(e.y);
            acc[j] = acc[j] + ex;
        }
    }

    float2* ob = (float2*)(out + (size_t)b * C + (size_t)h * CH);
    ob[t]         = make_float2(acc[0].x, acc[0].y);
    ob[t + BLOCK] = make_float2(acc[1].x, acc[1].y);
}

extern "C" void kernel_launch(void* const* d_in, const int* in_sizes, int n_in,
                              void* d_out, int out_size, void* d_ws, size_t ws_size,
                              hipStream_t stream) {
    const float* mo = (const float*)d_in[0];   // (B,K,6)
    const float* X  = (const float*)d_in[1];   // (B,C,2)
    float* out      = (float*)d_out;           // (B,C)

    mixture_kernel<<<dim3(B * HALVES), dim3(BLOCK), 0, stream>>>(mo, X, out);
}